// Round 1
// baseline (1368.935 us; speedup 1.0000x reference)
//
#include <hip/hip_runtime.h>
#include <cstdint>
#include <cstddef>

#define Bn 128
#define Ln 1024
#define Fn 128
#define Hn 64
#define NGn 256           // 4*H
#define NCn 16
#define IN_DIM (Hn + Fn*Hn)   // 8256

__device__ __forceinline__ float sigm(float x) { return 1.0f / (1.0f + expf(-x)); }

// Permuted-weight prep:
//   g(tid) = (tid&3)*64 + (tid>>6)*16 + ((tid>>2)&15)
// so that the 4 gates (i,f,o,c) of hidden unit u live in 4 adjacent lanes of one wave.
// Wh4[(f*16 + k4)*256 + tid] = W_gates[f][g(tid)][1+4k4 .. 4+4k4]   (float4, coalesced)
// Wx [f*256 + tid]           = W_gates[f][g(tid)][0]
// bgp[f*256 + tid]           = b_gates[f][g(tid)]
__global__ __launch_bounds__(256)
void prep_kernel(const float* __restrict__ Wg, const float* __restrict__ bg,
                 float4* __restrict__ Wh4, float* __restrict__ Wx, float* __restrict__ bgp)
{
    int f = blockIdx.x;
    int tid = threadIdx.x;
    int g = (tid & 3) * 64 + (tid >> 6) * 16 + ((tid >> 2) & 15);
    const float* src = Wg + ((size_t)f * NGn + g) * 65;
    Wx[f * NGn + tid]  = src[0];
    bgp[f * NGn + tid] = bg[f * NGn + g];
#pragma unroll
    for (int k4 = 0; k4 < 16; ++k4) {
        float4 v;
        v.x = src[1 + 4*k4 + 0];
        v.y = src[1 + 4*k4 + 1];
        v.z = src[1 + 4*k4 + 2];
        v.w = src[1 + 4*k4 + 3];
        Wh4[((size_t)f * 16 + k4) * NGn + tid] = v;
    }
}

template<bool PRE>
__global__ __launch_bounds__(256)
void lstm_main(const float* __restrict__ X, const int* __restrict__ lengths,
               const float4* __restrict__ Wh4, const float* __restrict__ Wx,
               const float* __restrict__ bgp,
               const float* __restrict__ Wg, const float* __restrict__ bg,
               const float* __restrict__ wdec, const float* __restrict__ bdec,
               const float* __restrict__ Wo, const float* __restrict__ bo,
               float* __restrict__ out)
{
    __shared__ __align__(16) float h_lds[Fn * Hn];   // 32 KB: full h state
    __shared__ float c_lds[Hn];
    __shared__ int   m_lds[Ln];
    __shared__ float x_lds[Ln];
    __shared__ float d_lds[Ln];
    __shared__ float wd_lds[Fn], bd_lds[Fn];
    __shared__ float red_lds[4 * NCn];
    __shared__ float logit_lds[NCn];

    const int b   = blockIdx.x;
    const int tid = threadIdx.x;
    const int l   = tid & 63;         // lane in wave
    const int w   = tid >> 6;         // wave index (0..3)
    const int q   = l & 3;            // gate index: 0=i,1=f,2=o,3=c
    const int u   = w * 16 + (l >> 2);// hidden unit owned by this lane group

    const float* mrow = X + ((size_t)b * 4 + 1) * Ln;
    const float* xrow = X + ((size_t)b * 4 + 2) * Ln;
    const float* drow = X + ((size_t)b * 4 + 3) * Ln;

    for (int i = tid; i < Fn * Hn; i += 256) h_lds[i] = 0.0f;
    if (tid < Hn) c_lds[tid] = 0.0f;
    if (tid < Fn) { wd_lds[tid] = wdec[tid]; bd_lds[tid] = bdec[tid]; }
    for (int i = tid; i < Ln; i += 256) {
        m_lds[i] = (int)mrow[i];
        x_lds[i] = xrow[i];
        d_lds[i] = drow[i];
    }
    __syncthreads();

    int len = lengths[b];
    if (len > Ln) len = Ln;

    const int g_raw = q * 64 + u;   // gate row this thread owns (raw layout)

    for (int j = 0; j < len; ++j) {
        const int   mj = m_lds[j];
        const float xj = x_lds[j];
        const float dj = d_lds[j];
        const float dec = expf(-fmaxf(0.0f, fmaf(wd_lds[mj], dj, bd_lds[mj])));

        const float4* hp = (const float4*)(h_lds + mj * Hn);
        float acc;
        float ah0 = 0.0f, ah1 = 0.0f, ah2 = 0.0f, ah3 = 0.0f;

        if (PRE) {
            acc = fmaf(Wx[mj * NGn + tid], xj, bgp[mj * NGn + tid]);
            const float4* wp = Wh4 + (size_t)mj * (16 * NGn) + tid;
#pragma unroll
            for (int k4 = 0; k4 < 16; ++k4) {
                float4 wv = wp[k4 * NGn];
                float4 hv = hp[k4];
                ah0 = fmaf(wv.x, hv.x, ah0);
                ah1 = fmaf(wv.y, hv.y, ah1);
                ah2 = fmaf(wv.z, hv.z, ah2);
                ah3 = fmaf(wv.w, hv.w, ah3);
            }
        } else {
            const float* row = Wg + ((size_t)mj * NGn + g_raw) * 65;
            acc = fmaf(row[0], xj, bg[mj * NGn + g_raw]);
#pragma unroll
            for (int k4 = 0; k4 < 16; ++k4) {
                float4 hv = hp[k4];
                ah0 = fmaf(row[1 + 4*k4 + 0], hv.x, ah0);
                ah1 = fmaf(row[1 + 4*k4 + 1], hv.y, ah1);
                ah2 = fmaf(row[1 + 4*k4 + 2], hv.z, ah2);
                ah3 = fmaf(row[1 + 4*k4 + 3], hv.w, ah3);
            }
        }
        acc = fmaf(dec, (ah0 + ah1) + (ah2 + ah3), acc);

        // exchange the 4 gates of unit u within the wave
        const int base = l & ~3;
        const float gi = __shfl(acc, base + 0, 64);
        const float gf = __shfl(acc, base + 1, 64);
        const float go = __shfl(acc, base + 2, 64);
        const float gc = __shfl(acc, base + 3, 64);

        __syncthreads();   // all h-row reads done before anyone writes

        const float c_old = c_lds[u];
        const float c_new = fmaf(sigm(gf), c_old, sigm(gi) * tanhf(gc));
        if (q == 0) {
            c_lds[u] = c_new;
            h_lds[mj * Hn + u] = sigm(go) * tanhf(c_new);
        }
        __syncthreads();   // state writes visible before next step's reads
    }

    // ---- output head: logits = W_out @ [c; h.flatten()] + b_out, softmax ----
    float p[NCn];
#pragma unroll
    for (int c = 0; c < NCn; ++c) p[c] = 0.0f;
    for (int i = tid; i < IN_DIM; i += 256) {
        const float fv = (i < Hn) ? c_lds[i] : h_lds[i - Hn];
#pragma unroll
        for (int c = 0; c < NCn; ++c)
            p[c] = fmaf(Wo[(size_t)c * IN_DIM + i], fv, p[c]);
    }
#pragma unroll
    for (int c = 0; c < NCn; ++c) {
        float v = p[c];
#pragma unroll
        for (int off = 32; off > 0; off >>= 1) v += __shfl_down(v, off, 64);
        if (l == 0) red_lds[w * NCn + c] = v;
    }
    __syncthreads();
    if (tid < NCn) {
        logit_lds[tid] = red_lds[tid] + red_lds[NCn + tid] +
                         red_lds[2 * NCn + tid] + red_lds[3 * NCn + tid] + bo[tid];
    }
    __syncthreads();
    if (tid == 0) {
        float mx = logit_lds[0];
        for (int c = 1; c < NCn; ++c) mx = fmaxf(mx, logit_lds[c]);
        float e[NCn], s = 0.0f;
        for (int c = 0; c < NCn; ++c) { e[c] = expf(logit_lds[c] - mx); s += e[c]; }
        const float inv = 1.0f / s;
        for (int c = 0; c < NCn; ++c) out[(size_t)b * NCn + c] = e[c] * inv;
    }
}

extern "C" void kernel_launch(void* const* d_in, const int* in_sizes, int n_in,
                              void* d_out, int out_size, void* d_ws, size_t ws_size,
                              hipStream_t stream)
{
    const float* X      = (const float*)d_in[0];
    const int*   len    = (const int*)  d_in[1];
    const float* Wg     = (const float*)d_in[2];
    const float* bg     = (const float*)d_in[3];
    const float* wdec   = (const float*)d_in[4];
    const float* bdec   = (const float*)d_in[5];
    const float* Wo     = (const float*)d_in[6];
    const float* bo     = (const float*)d_in[7];
    float*       out    = (float*)d_out;

    const size_t wh4_bytes = (size_t)Fn * 16 * NGn * sizeof(float4); // 8,388,608
    const size_t wx_bytes  = (size_t)Fn * NGn * sizeof(float);       // 131,072
    const size_t need      = wh4_bytes + 2 * wx_bytes;

    if (ws_size >= need) {
        float4* Wh4 = (float4*)d_ws;
        float*  Wx  = (float*)((char*)d_ws + wh4_bytes);
        float*  bgp = Wx + (size_t)Fn * NGn;
        prep_kernel<<<Fn, 256, 0, stream>>>(Wg, bg, Wh4, Wx, bgp);
        lstm_main<true><<<Bn, 256, 0, stream>>>(X, len, Wh4, Wx, bgp,
                                                Wg, bg, wdec, bdec, Wo, bo, out);
    } else {
        lstm_main<false><<<Bn, 256, 0, stream>>>(X, len, nullptr, nullptr, nullptr,
                                                 Wg, bg, wdec, bdec, Wo, bo, out);
    }
}

// Round 2
// 1138.505 us; speedup vs baseline: 1.2024x; 1.2024x over previous
//
#include <hip/hip_runtime.h>
#include <cstdint>
#include <cstddef>

#define Bn 128
#define Ln 1024
#define Fn 128
#define Hn 64
#define NGn 256           // 4*H
#define NCn 16
#define IN_DIM (Hn + Fn*Hn)   // 8256

__device__ __forceinline__ float fsigm(float x) {
    return __fdividef(1.0f, 1.0f + __expf(-x));
}
__device__ __forceinline__ float ftanh(float x) {
    // 1 - 2/(e^{2x}+1); saturates correctly for |x| large
    float e = __expf(2.0f * x);
    return 1.0f - __fdividef(2.0f, e + 1.0f);
}
__device__ __forceinline__ float sigm_slow(float x) { return 1.0f / (1.0f + expf(-x)); }

// Permuted-weight prep:
//   g(tid) = (tid&3)*64 + (tid>>6)*16 + ((tid>>2)&15)
// so the 4 gates (i,f,o,c) of hidden unit u live in 4 adjacent lanes of one wave.
// Wh4[(f*16 + k4)*256 + tid] = W_gates[f][g(tid)][1+4k4 .. 4+4k4]  (float4, coalesced)
// WB2[f*256 + tid]           = (W_gates[f][g(tid)][0], b_gates[f][g(tid)])
__global__ __launch_bounds__(256)
void prep_kernel(const float* __restrict__ Wg, const float* __restrict__ bg,
                 float4* __restrict__ Wh4, float2* __restrict__ WB2)
{
    int f = blockIdx.x;
    int tid = threadIdx.x;
    int g = (tid & 3) * 64 + (tid >> 6) * 16 + ((tid >> 2) & 15);
    const float* src = Wg + ((size_t)f * NGn + g) * 65;
    WB2[f * NGn + tid] = make_float2(src[0], bg[f * NGn + g]);
#pragma unroll
    for (int k4 = 0; k4 < 16; ++k4) {
        float4 v;
        v.x = src[1 + 4*k4 + 0];
        v.y = src[1 + 4*k4 + 1];
        v.z = src[1 + 4*k4 + 2];
        v.w = src[1 + 4*k4 + 3];
        Wh4[((size_t)f * 16 + k4) * NGn + tid] = v;
    }
}

// ---- register prefetch of one step's weight slab (66 KB/block -> 66 regs/thread)
#define PF(MN, WN, WBN)                                                         \
    do {                                                                        \
        const float4* wp_ = Wh4 + ((size_t)(MN) << 12) + tid;                   \
        _Pragma("unroll")                                                       \
        for (int k4_ = 0; k4_ < 16; ++k4_) WN[k4_] = wp_[k4_ * NGn];            \
        WBN = WB2[(MN) * NGn + tid];                                            \
    } while (0)

// One recurrence step using weight buffer WC, prefetching step PFI into WN.
// Raw s_barrier + lgkmcnt(0): LDS ordering preserved, global prefetch loads
// stay in flight across the barrier (no vmcnt drain).
#define STEP(JIDX, WC, WBC, WN, WBN, PFI)                                       \
    do {                                                                        \
        const int   mj_ = m_cur;                                                \
        const float xj_ = x_lds[JIDX];                                          \
        const float dj_ = d_lds[JIDX];                                          \
        const int   mn_ = m_lds[PFI];                                           \
        PF(mn_, WN, WBN);                                                       \
        const float dec_ = __expf(-fmaxf(0.0f, fmaf(wd_lds[mj_], dj_, bd_lds[mj_]))); \
        const float4* hp_ = (const float4*)(h_lds + mj_ * Hn);                  \
        float a0_ = 0.f, a1_ = 0.f, a2_ = 0.f, a3_ = 0.f;                       \
        _Pragma("unroll")                                                       \
        for (int k4_ = 0; k4_ < 16; ++k4_) {                                    \
            float4 hv_ = hp_[k4_];                                              \
            a0_ = fmaf(WC[k4_].x, hv_.x, a0_);                                  \
            a1_ = fmaf(WC[k4_].y, hv_.y, a1_);                                  \
            a2_ = fmaf(WC[k4_].z, hv_.z, a2_);                                  \
            a3_ = fmaf(WC[k4_].w, hv_.w, a3_);                                  \
        }                                                                       \
        float acc_ = fmaf(WBC.x, xj_, WBC.y);                                   \
        acc_ = fmaf(dec_, (a0_ + a1_) + (a2_ + a3_), acc_);                     \
        const int base_ = l & ~3;                                               \
        const float gi_ = __shfl(acc_, base_ + 0, 64);                          \
        const float gf_ = __shfl(acc_, base_ + 1, 64);                          \
        const float go_ = __shfl(acc_, base_ + 2, 64);                          \
        const float gc_ = __shfl(acc_, base_ + 3, 64);                          \
        asm volatile("s_waitcnt lgkmcnt(0)" ::: "memory");                      \
        __builtin_amdgcn_s_barrier();   /* all h-row reads done */              \
        const float cn_ = fmaf(fsigm(gf_), c_lds[u], fsigm(gi_) * ftanh(gc_));  \
        if (q == 0) {                                                           \
            c_lds[u] = cn_;                                                     \
            h_lds[mj_ * Hn + u] = fsigm(go_) * ftanh(cn_);                      \
        }                                                                       \
        m_cur = mn_;                                                            \
        asm volatile("s_waitcnt lgkmcnt(0)" ::: "memory");                      \
        __builtin_amdgcn_s_barrier();   /* state writes visible */              \
    } while (0)

template<bool PRE>
__global__ __launch_bounds__(256, 1)
void lstm_main(const float* __restrict__ X, const int* __restrict__ lengths,
               const float4* __restrict__ Wh4, const float2* __restrict__ WB2,
               const float* __restrict__ Wg, const float* __restrict__ bg,
               const float* __restrict__ wdec, const float* __restrict__ bdec,
               const float* __restrict__ Wo, const float* __restrict__ bo,
               float* __restrict__ out)
{
    __shared__ __align__(16) float h_lds[Fn * Hn];   // 32 KB: full h state
    __shared__ float c_lds[Hn];
    __shared__ int   m_lds[Ln];
    __shared__ float x_lds[Ln];
    __shared__ float d_lds[Ln];
    __shared__ float wd_lds[Fn], bd_lds[Fn];
    __shared__ float red_lds[4 * NCn];
    __shared__ float logit_lds[NCn];

    const int b   = blockIdx.x;
    const int tid = threadIdx.x;
    const int l   = tid & 63;          // lane in wave
    const int w   = tid >> 6;          // wave index (0..3)
    const int q   = l & 3;             // gate index: 0=i,1=f,2=o,3=c
    const int u   = w * 16 + (l >> 2); // hidden unit owned by this lane group

    const float* mrow = X + ((size_t)b * 4 + 1) * Ln;
    const float* xrow = X + ((size_t)b * 4 + 2) * Ln;
    const float* drow = X + ((size_t)b * 4 + 3) * Ln;

    for (int i = tid; i < Fn * Hn; i += 256) h_lds[i] = 0.0f;
    if (tid < Hn) c_lds[tid] = 0.0f;
    if (tid < Fn) { wd_lds[tid] = wdec[tid]; bd_lds[tid] = bdec[tid]; }
    for (int i = tid; i < Ln; i += 256) {
        m_lds[i] = (int)mrow[i];
        x_lds[i] = xrow[i];
        d_lds[i] = drow[i];
    }
    __syncthreads();

    int len = lengths[b];
    if (len > Ln) len = Ln;

    if (PRE) {
        if (len > 0) {
            float4 wA[16]; float2 wbA;
            float4 wB[16]; float2 wbB;
            int m_cur = m_lds[0];
            PF(m_cur, wA, wbA);
            int j = 0;
            for (; j + 1 < len; j += 2) {
                const int pf1 = j + 1;                     // < len
                const int pf2 = (j + 2 < len) ? j + 2 : len - 1;
                STEP(j,     wA, wbA, wB, wbB, pf1);
                STEP(j + 1, wB, wbB, wA, wbA, pf2);
            }
            if (j < len) {
                STEP(j, wA, wbA, wB, wbB, j);
            }
        }
    } else {
        // slow fallback (no workspace): read raw W each step
        const int g_raw = q * 64 + u;
        for (int j = 0; j < len; ++j) {
            const int   mj = m_lds[j];
            const float xj = x_lds[j];
            const float dj = d_lds[j];
            const float dec = expf(-fmaxf(0.0f, fmaf(wd_lds[mj], dj, bd_lds[mj])));
            const float4* hp = (const float4*)(h_lds + mj * Hn);
            const float* row = Wg + ((size_t)mj * NGn + g_raw) * 65;
            float acc = fmaf(row[0], xj, bg[mj * NGn + g_raw]);
            float a0 = 0.f, a1 = 0.f, a2 = 0.f, a3 = 0.f;
#pragma unroll
            for (int k4 = 0; k4 < 16; ++k4) {
                float4 hv = hp[k4];
                a0 = fmaf(row[1 + 4*k4 + 0], hv.x, a0);
                a1 = fmaf(row[1 + 4*k4 + 1], hv.y, a1);
                a2 = fmaf(row[1 + 4*k4 + 2], hv.z, a2);
                a3 = fmaf(row[1 + 4*k4 + 3], hv.w, a3);
            }
            acc = fmaf(dec, (a0 + a1) + (a2 + a3), acc);
            const int base = l & ~3;
            const float gi = __shfl(acc, base + 0, 64);
            const float gf = __shfl(acc, base + 1, 64);
            const float go = __shfl(acc, base + 2, 64);
            const float gc = __shfl(acc, base + 3, 64);
            __syncthreads();
            const float c_new = fmaf(sigm_slow(gf), c_lds[u], sigm_slow(gi) * tanhf(gc));
            if (q == 0) {
                c_lds[u] = c_new;
                h_lds[mj * Hn + u] = sigm_slow(go) * tanhf(c_new);
            }
            __syncthreads();
        }
    }

    // ---- output head: logits = W_out @ [c; h.flatten()] + b_out, softmax ----
    float p[NCn];
#pragma unroll
    for (int c = 0; c < NCn; ++c) p[c] = 0.0f;
    for (int i = tid; i < IN_DIM; i += 256) {
        const float fv = (i < Hn) ? c_lds[i] : h_lds[i - Hn];
#pragma unroll
        for (int c = 0; c < NCn; ++c)
            p[c] = fmaf(Wo[(size_t)c * IN_DIM + i], fv, p[c]);
    }
#pragma unroll
    for (int c = 0; c < NCn; ++c) {
        float v = p[c];
#pragma unroll
        for (int off = 32; off > 0; off >>= 1) v += __shfl_down(v, off, 64);
        if (l == 0) red_lds[w * NCn + c] = v;
    }
    __syncthreads();
    if (tid < NCn) {
        logit_lds[tid] = red_lds[tid] + red_lds[NCn + tid] +
                         red_lds[2 * NCn + tid] + red_lds[3 * NCn + tid] + bo[tid];
    }
    __syncthreads();
    if (tid == 0) {
        float mx = logit_lds[0];
        for (int c = 1; c < NCn; ++c) mx = fmaxf(mx, logit_lds[c]);
        float e[NCn], s = 0.0f;
        for (int c = 0; c < NCn; ++c) { e[c] = expf(logit_lds[c] - mx); s += e[c]; }
        const float inv = 1.0f / s;
        for (int c = 0; c < NCn; ++c) out[(size_t)b * NCn + c] = e[c] * inv;
    }
}

extern "C" void kernel_launch(void* const* d_in, const int* in_sizes, int n_in,
                              void* d_out, int out_size, void* d_ws, size_t ws_size,
                              hipStream_t stream)
{
    const float* X      = (const float*)d_in[0];
    const int*   len    = (const int*)  d_in[1];
    const float* Wg     = (const float*)d_in[2];
    const float* bg     = (const float*)d_in[3];
    const float* wdec   = (const float*)d_in[4];
    const float* bdec   = (const float*)d_in[5];
    const float* Wo     = (const float*)d_in[6];
    const float* bo     = (const float*)d_in[7];
    float*       out    = (float*)d_out;

    const size_t wh4_bytes = (size_t)Fn * 16 * NGn * sizeof(float4); // 8,388,608
    const size_t wb2_bytes = (size_t)Fn * NGn * sizeof(float2);      // 262,144
    const size_t need      = wh4_bytes + wb2_bytes;

    if (ws_size >= need) {
        float4* Wh4 = (float4*)d_ws;
        float2* WB2 = (float2*)((char*)d_ws + wh4_bytes);
        prep_kernel<<<Fn, 256, 0, stream>>>(Wg, bg, Wh4, WB2);
        lstm_main<true><<<Bn, 256, 0, stream>>>(X, len, Wh4, WB2,
                                                Wg, bg, wdec, bdec, Wo, bo, out);
    } else {
        lstm_main<false><<<Bn, 256, 0, stream>>>(X, len, nullptr, nullptr,
                                                 Wg, bg, wdec, bdec, Wo, bo, out);
    }
}

// Round 4
// 902.234 us; speedup vs baseline: 1.5173x; 1.2619x over previous
//
#include <hip/hip_runtime.h>
#include <cstdint>
#include <cstddef>

#define Bn 128
#define Ln 1024
#define Fn 128
#define Hn 64
#define NGn 256           // 4*H
#define NCn 16
#define IN_DIM (Hn + Fn*Hn)   // 8256

typedef float    f32x4 __attribute__((ext_vector_type(4)));
typedef _Float16 f16x8 __attribute__((ext_vector_type(8)));

typedef __attribute__((address_space(1))) const void* gas_t;
typedef __attribute__((address_space(3))) void*       las_t;

// ---- dynamic LDS carve (bytes) ----
#define OFF_H    0                       // 32768  h state f32
#define OFF_W    32768                   // 2 x 32768 W f16 dbuf
#define OFF_WB   (OFF_W + 65536)         // 2 x 2048 (wx plane 1024 | b plane 1024)
#define OFF_M    (OFF_WB + 4096)         // 4096
#define OFF_X    (OFF_M + 4096)          // 4096
#define OFF_D    (OFF_X + 4096)          // 4096
#define OFF_C    (OFF_D + 4096)          // 256
#define OFF_WD   (OFF_C + 256)           // 512
#define OFF_BD   (OFF_WD + 512)          // 512
#define OFF_RED  (OFF_BD + 512)          // 256
#define OFF_LOG  (OFF_RED + 256)         // 64
#define LDS_TOTAL (OFF_LOG + 64)         // 116288 - fits 160K/CU

__device__ __forceinline__ float fsigm(float x) {
    return __fdividef(1.0f, 1.0f + __expf(-x));
}
__device__ __forceinline__ float ftanh(float x) {
    float e = __expf(2.0f * x);
    return 1.0f - __fdividef(2.0f, e + 1.0f);
}
__device__ __forceinline__ float sigm_slow(float x) { return 1.0f / (1.0f + expf(-x)); }

template<int K>
__device__ __forceinline__ float quad_bcast(float v) {
    int i = __builtin_amdgcn_mov_dpp(__float_as_int(v), K * 0x55, 0xf, 0xf, true);
    return __int_as_float(i);
}

// gate-row owned by thread tid: g(tid) = (tid&3)*64 + (tid>>6)*16 + ((tid>>2)&15)
// Gw[((f*8 + r)*256 + tid)*8 + e] = (f16) W_gates[f][g(tid)][1 + 8r + e]
// Gwx[f*256 + tid] = W_gates[f][g(tid)][0];  Gb[f*256 + tid] = b_gates[f][g(tid)]
__global__ __launch_bounds__(256)
void prep_f16(const float* __restrict__ Wg, const float* __restrict__ bg,
              _Float16* __restrict__ Gw, float* __restrict__ Gwx, float* __restrict__ Gb)
{
    const int f = blockIdx.x, tid = threadIdx.x;
    const int g = (tid & 3) * 64 + (tid >> 6) * 16 + ((tid >> 2) & 15);
    const float* src = Wg + ((size_t)f * NGn + g) * 65;
    Gwx[f * NGn + tid] = src[0];
    Gb [f * NGn + tid] = bg[f * NGn + g];
#pragma unroll
    for (int r = 0; r < 8; ++r) {
        f16x8 v;
#pragma unroll
        for (int e = 0; e < 8; ++e) v[e] = (_Float16)src[1 + 8*r + e];
        *(f16x8*)(Gw + (((size_t)f * 8 + r) * NGn + tid) * 8) = v;
    }
}

// Stage one step's slab into LDS buffer SEL via global_load_lds.
// Exactly 10 VMEM ops per wave: 8 x 16B (W) + 2 x 4B (wx, b planes).
#define ISSUE_LDS(SEL, MN)                                                      \
    do {                                                                        \
        char* wdst_ = smem + OFF_W + (SEL) * 32768;                             \
        const _Float16* gsrc_ = Gw + ((size_t)(MN) * 8 * NGn + tid) * 8;        \
        _Pragma("unroll")                                                       \
        for (int i_ = 0; i_ < 8; ++i_)                                          \
            __builtin_amdgcn_global_load_lds(                                   \
                (gas_t)(const void*)(gsrc_ + i_ * (NGn * 8)),                   \
                (las_t)(void*)(wdst_ + (i_ * 256 + w * 64) * 16), 16, 0, 0);    \
        char* bdst_ = smem + OFF_WB + (SEL) * 2048;                             \
        __builtin_amdgcn_global_load_lds(                                       \
            (gas_t)(const void*)(Gwx + (MN) * NGn + tid),                       \
            (las_t)(void*)(bdst_ + w * 256), 4, 0, 0);                          \
        __builtin_amdgcn_global_load_lds(                                       \
            (gas_t)(const void*)(Gb + (MN) * NGn + tid),                        \
            (las_t)(void*)(bdst_ + 1024 + w * 256), 4, 0, 0);                   \
    } while (0)

// One recurrence step consuming LDS slab SEL; issues slab for step J+2 into SEL.
#define STEPJ(J, SEL)                                                           \
    {                                                                           \
        const int   j_   = (J);                                                 \
        const int   mj_  = m_lds[j_];                                           \
        const float xj_  = x_lds[j_];                                           \
        const float dj_  = d_lds[j_];                                           \
        const int   pfi_ = (j_ + 2 < len) ? (j_ + 2) : (len - 1);               \
        const int   mn_  = m_lds[pfi_];                                         \
        const float wdv_ = wd_lds[mj_], bdv_ = bd_lds[mj_];                     \
        const char* wsrc_ = smem + OFF_W + (SEL) * 32768;                       \
        f16x8 wv_[8];                                                           \
        _Pragma("unroll")                                                       \
        for (int r_ = 0; r_ < 8; ++r_)                                          \
            wv_[r_] = *(const f16x8*)(wsrc_ + (r_ * 256 + tid) * 16);           \
        const f32x4* hp_ = (const f32x4*)(h_lds + mj_ * Hn);                    \
        f32x4 hv_[16];                                                          \
        _Pragma("unroll")                                                       \
        for (int k_ = 0; k_ < 16; ++k_) hv_[k_] = hp_[k_];                      \
        const float co_ = c_lds[u];                                             \
        const float* wbp_ = (const float*)(smem + OFF_WB + (SEL) * 2048);       \
        const float wx_ = wbp_[tid];                                            \
        const float bb_ = wbp_[256 + tid];                                      \
        asm volatile("s_waitcnt lgkmcnt(0)" ::: "memory");                      \
        __builtin_amdgcn_sched_barrier(0);                                      \
        __builtin_amdgcn_s_barrier();   /* B1: all reads of slab+state done */  \
        ISSUE_LDS(SEL, mn_);                                                    \
        const float dec_ = __expf(-fmaxf(0.0f, fmaf(wdv_, dj_, bdv_)));         \
        float a0_ = 0.f, a1_ = 0.f, a2_ = 0.f, a3_ = 0.f;                       \
        _Pragma("unroll")                                                       \
        for (int r_ = 0; r_ < 8; ++r_) {                                        \
            a0_ = fmaf((float)wv_[r_][0], hv_[2*r_][0], a0_);                   \
            a1_ = fmaf((float)wv_[r_][1], hv_[2*r_][1], a1_);                   \
            a2_ = fmaf((float)wv_[r_][2], hv_[2*r_][2], a2_);                   \
            a3_ = fmaf((float)wv_[r_][3], hv_[2*r_][3], a3_);                   \
            a0_ = fmaf((float)wv_[r_][4], hv_[2*r_+1][0], a0_);                 \
            a1_ = fmaf((float)wv_[r_][5], hv_[2*r_+1][1], a1_);                 \
            a2_ = fmaf((float)wv_[r_][6], hv_[2*r_+1][2], a2_);                 \
            a3_ = fmaf((float)wv_[r_][7], hv_[2*r_+1][3], a3_);                 \
        }                                                                       \
        float acc_ = fmaf(wx_, xj_, bb_);                                       \
        acc_ = fmaf(dec_, (a0_ + a1_) + (a2_ + a3_), acc_);                     \
        const float gi_ = quad_bcast<0>(acc_);                                  \
        const float gf_ = quad_bcast<1>(acc_);                                  \
        const float go_ = quad_bcast<2>(acc_);                                  \
        const float gc_ = quad_bcast<3>(acc_);                                  \
        const float cn_ = fmaf(fsigm(gf_), co_, fsigm(gi_) * ftanh(gc_));       \
        if (q == 0) {                                                           \
            c_lds[u] = cn_;                                                     \
            h_lds[mj_ * Hn + u] = fsigm(go_) * ftanh(cn_);                      \
        }                                                                       \
        asm volatile("s_waitcnt vmcnt(10) lgkmcnt(0)" ::: "memory");            \
        __builtin_amdgcn_sched_barrier(0);                                      \
        __builtin_amdgcn_s_barrier();   /* B2: state + slab j+1 visible */      \
    }

__global__ __launch_bounds__(256, 1)
void lstm_pre(const float* __restrict__ X, const int* __restrict__ lengths,
              const _Float16* __restrict__ Gw, const float* __restrict__ Gwx,
              const float* __restrict__ Gb,
              const float* __restrict__ wdec, const float* __restrict__ bdec,
              const float* __restrict__ Wo, const float* __restrict__ bo,
              float* __restrict__ out)
{
    extern __shared__ char smem[];
    float* h_lds  = (float*)(smem + OFF_H);
    float* c_lds  = (float*)(smem + OFF_C);
    int*   m_lds  = (int*)  (smem + OFF_M);
    float* x_lds  = (float*)(smem + OFF_X);
    float* d_lds  = (float*)(smem + OFF_D);
    float* wd_lds = (float*)(smem + OFF_WD);
    float* bd_lds = (float*)(smem + OFF_BD);
    float* red_lds   = (float*)(smem + OFF_RED);
    float* logit_lds = (float*)(smem + OFF_LOG);

    const int b   = blockIdx.x;
    const int tid = threadIdx.x;
    const int l   = tid & 63;
    const int w   = tid >> 6;
    const int q   = l & 3;             // 0=i,1=f,2=o,3=c
    const int u   = w * 16 + (l >> 2); // hidden unit

    const float* mrow = X + ((size_t)b * 4 + 1) * Ln;
    const float* xrow = X + ((size_t)b * 4 + 2) * Ln;
    const float* drow = X + ((size_t)b * 4 + 3) * Ln;

    for (int i = tid; i < Fn * Hn; i += 256) h_lds[i] = 0.0f;
    if (tid < Hn) c_lds[tid] = 0.0f;
    if (tid < Fn) { wd_lds[tid] = wdec[tid]; bd_lds[tid] = bdec[tid]; }
    for (int i = tid; i < Ln; i += 256) {
        m_lds[i] = (int)mrow[i];
        x_lds[i] = xrow[i];
        d_lds[i] = drow[i];
    }
    __syncthreads();

    int len = lengths[b];
    if (len > Ln) len = Ln;

    if (len > 0) {
        ISSUE_LDS(0, m_lds[0]);
        {
            const int i1 = (1 < len) ? 1 : 0;
            ISSUE_LDS(1, m_lds[i1]);
        }
        asm volatile("s_waitcnt vmcnt(10)" ::: "memory");
        __builtin_amdgcn_sched_barrier(0);
        __builtin_amdgcn_s_barrier();    // slab 0 staged for everyone

        int j = 0;
        for (;;) {
            STEPJ(j, 0); if (++j >= len) break;
            STEPJ(j, 1); if (++j >= len) break;
        }
        asm volatile("s_waitcnt vmcnt(0)" ::: "memory");  // drain in-flight LDS writes
    }
    __syncthreads();

    // ---- output head: logits = W_out @ [c; h.flatten()] + b_out, softmax ----
    float p[NCn];
#pragma unroll
    for (int c = 0; c < NCn; ++c) p[c] = 0.0f;
    for (int i = tid; i < IN_DIM; i += 256) {
        const float fv = (i < Hn) ? c_lds[i] : h_lds[i - Hn];
#pragma unroll
        for (int c = 0; c < NCn; ++c)
            p[c] = fmaf(Wo[(size_t)c * IN_DIM + i], fv, p[c]);
    }
#pragma unroll
    for (int c = 0; c < NCn; ++c) {
        float v = p[c];
#pragma unroll
        for (int off = 32; off > 0; off >>= 1) v += __shfl_down(v, off, 64);
        if (l == 0) red_lds[w * NCn + c] = v;
    }
    __syncthreads();
    if (tid < NCn) {
        logit_lds[tid] = red_lds[tid] + red_lds[NCn + tid] +
                         red_lds[2 * NCn + tid] + red_lds[3 * NCn + tid] + bo[tid];
    }
    __syncthreads();
    if (tid == 0) {
        float mx = logit_lds[0];
        for (int c = 1; c < NCn; ++c) mx = fmaxf(mx, logit_lds[c]);
        float e[NCn], s = 0.0f;
        for (int c = 0; c < NCn; ++c) { e[c] = expf(logit_lds[c] - mx); s += e[c]; }
        const float inv = 1.0f / s;
        for (int c = 0; c < NCn; ++c) out[(size_t)b * NCn + c] = e[c] * inv;
    }
}

// ---- fallback (no workspace): raw f32 weights each step ----
__global__ __launch_bounds__(256)
void lstm_fallback(const float* __restrict__ X, const int* __restrict__ lengths,
                   const float* __restrict__ Wg, const float* __restrict__ bg,
                   const float* __restrict__ wdec, const float* __restrict__ bdec,
                   const float* __restrict__ Wo, const float* __restrict__ bo,
                   float* __restrict__ out)
{
    __shared__ __align__(16) float h_lds[Fn * Hn];
    __shared__ float c_lds[Hn];
    __shared__ int   m_lds[Ln];
    __shared__ float x_lds[Ln];
    __shared__ float d_lds[Ln];
    __shared__ float wd_lds[Fn], bd_lds[Fn];
    __shared__ float red_lds[4 * NCn];
    __shared__ float logit_lds[NCn];

    const int b   = blockIdx.x;
    const int tid = threadIdx.x;
    const int l   = tid & 63;
    const int w   = tid >> 6;
    const int q   = l & 3;
    const int u   = w * 16 + (l >> 2);

    const float* mrow = X + ((size_t)b * 4 + 1) * Ln;
    const float* xrow = X + ((size_t)b * 4 + 2) * Ln;
    const float* drow = X + ((size_t)b * 4 + 3) * Ln;

    for (int i = tid; i < Fn * Hn; i += 256) h_lds[i] = 0.0f;
    if (tid < Hn) c_lds[tid] = 0.0f;
    if (tid < Fn) { wd_lds[tid] = wdec[tid]; bd_lds[tid] = bdec[tid]; }
    for (int i = tid; i < Ln; i += 256) {
        m_lds[i] = (int)mrow[i];
        x_lds[i] = xrow[i];
        d_lds[i] = drow[i];
    }
    __syncthreads();

    int len = lengths[b];
    if (len > Ln) len = Ln;
    const int g_raw = q * 64 + u;

    for (int j = 0; j < len; ++j) {
        const int   mj = m_lds[j];
        const float xj = x_lds[j];
        const float dj = d_lds[j];
        const float dec = expf(-fmaxf(0.0f, fmaf(wd_lds[mj], dj, bd_lds[mj])));
        const float4* hp = (const float4*)(h_lds + mj * Hn);
        const float* row = Wg + ((size_t)mj * NGn + g_raw) * 65;
        float acc = fmaf(row[0], xj, bg[mj * NGn + g_raw]);
        float a0 = 0.f, a1 = 0.f, a2 = 0.f, a3 = 0.f;
#pragma unroll
        for (int k4 = 0; k4 < 16; ++k4) {
            float4 hv = hp[k4];
            a0 = fmaf(row[1 + 4*k4 + 0], hv.x, a0);
            a1 = fmaf(row[1 + 4*k4 + 1], hv.y, a1);
            a2 = fmaf(row[1 + 4*k4 + 2], hv.z, a2);
            a3 = fmaf(row[1 + 4*k4 + 3], hv.w, a3);
        }
        acc = fmaf(dec, (a0 + a1) + (a2 + a3), acc);
        const int base = l & ~3;
        const float gi = __shfl(acc, base + 0, 64);
        const float gf = __shfl(acc, base + 1, 64);
        const float go = __shfl(acc, base + 2, 64);
        const float gc = __shfl(acc, base + 3, 64);
        __syncthreads();
        const float c_new = fmaf(sigm_slow(gf), c_lds[u], sigm_slow(gi) * tanhf(gc));
        if (q == 0) {
            c_lds[u] = c_new;
            h_lds[mj * Hn + u] = sigm_slow(go) * tanhf(c_new);
        }
        __syncthreads();
    }

    float p[NCn];
#pragma unroll
    for (int c = 0; c < NCn; ++c) p[c] = 0.0f;
    for (int i = tid; i < IN_DIM; i += 256) {
        const float fv = (i < Hn) ? c_lds[i] : h_lds[i - Hn];
#pragma unroll
        for (int c = 0; c < NCn; ++c)
            p[c] = fmaf(Wo[(size_t)c * IN_DIM + i], fv, p[c]);
    }
#pragma unroll
    for (int c = 0; c < NCn; ++c) {
        float v = p[c];
#pragma unroll
        for (int off = 32; off > 0; off >>= 1) v += __shfl_down(v, off, 64);
        if (l == 0) red_lds[w * NCn + c] = v;
    }
    __syncthreads();
    if (tid < NCn) {
        logit_lds[tid] = red_lds[tid] + red_lds[NCn + tid] +
                         red_lds[2 * NCn + tid] + red_lds[3 * NCn + tid] + bo[tid];
    }
    __syncthreads();
    if (tid == 0) {
        float mx = logit_lds[0];
        for (int c = 1; c < NCn; ++c) mx = fmaxf(mx, logit_lds[c]);
        float e[NCn], s = 0.0f;
        for (int c = 0; c < NCn; ++c) { e[c] = expf(logit_lds[c] - mx); s += e[c]; }
        const float inv = 1.0f / s;
        for (int c = 0; c < NCn; ++c) out[(size_t)b * NCn + c] = e[c] * inv;
    }
}

extern "C" void kernel_launch(void* const* d_in, const int* in_sizes, int n_in,
                              void* d_out, int out_size, void* d_ws, size_t ws_size,
                              hipStream_t stream)
{
    const float* X      = (const float*)d_in[0];
    const int*   len    = (const int*)  d_in[1];
    const float* Wg     = (const float*)d_in[2];
    const float* bg     = (const float*)d_in[3];
    const float* wdec   = (const float*)d_in[4];
    const float* bdec   = (const float*)d_in[5];
    const float* Wo     = (const float*)d_in[6];
    const float* bo     = (const float*)d_in[7];
    float*       out    = (float*)d_out;

    const size_t gw_bytes = (size_t)Fn * 8 * NGn * 8 * sizeof(_Float16); // 4,194,304
    const size_t gx_bytes = (size_t)Fn * NGn * sizeof(float);            // 131,072
    const size_t need     = gw_bytes + 2 * gx_bytes;

    if (ws_size >= need) {
        _Float16* Gw  = (_Float16*)d_ws;
        float*    Gwx = (float*)((char*)d_ws + gw_bytes);
        float*    Gb  = Gwx + (size_t)Fn * NGn;
        prep_f16<<<Fn, 256, 0, stream>>>(Wg, bg, Gw, Gwx, Gb);
        (void)hipFuncSetAttribute((const void*)lstm_pre,
                                  hipFuncAttributeMaxDynamicSharedMemorySize,
                                  LDS_TOTAL);
        lstm_pre<<<Bn, 256, LDS_TOTAL, stream>>>(X, len, Gw, Gwx, Gb,
                                                 wdec, bdec, Wo, bo, out);
    } else {
        lstm_fallback<<<Bn, 256, 0, stream>>>(X, len, Wg, bg,
                                              wdec, bdec, Wo, bo, out);
    }
}